// Round 12
// baseline (382.628 us; speedup 1.0000x reference)
//
#include <hip/hip_runtime.h>
#include <hip/hip_cooperative_groups.h>
#include <math.h>
namespace cg = cooperative_groups;

#define N 80
#define D 512
#define NV (N*N)        // 6400
#define CQ 6241.000001  // (n1-1)*(n2-1) + ridge
#define CG_MAX 16
#define SMEM_DBL 6568   // 52,544 B < 64 KB

// ---- static device scratch (inter-phase) ----
__device__ double g_Mp0[N*N];
__device__ float  g_WT[D*D];
__device__ double g_e[2][N*D];
__device__ double g_P[NV];

// ============ phase device functions (shared by coop + fallback) ============

// transpose one 32x32 tile of W into WT; wtb in [0,256)
__device__ __forceinline__ void phase_wt(int wtb, int tid, const float* __restrict__ W,
                                         double* smem) {
    float* t32 = reinterpret_cast<float*>(smem);       // 32*33 floats
    int c0 = (wtb & 15)*32, k0 = (wtb >> 4)*32;
    int tx = tid & 31, ty = tid >> 5;                  // 32 x 8
    #pragma unroll
    for (int j = 0; j < 4; ++j) t32[(ty+8*j)*33 + tx] = W[(size_t)(k0+ty+8*j)*D + c0+tx];
    __syncthreads();
    #pragma unroll
    for (int j = 0; j < 4; ++j) g_WT[(size_t)(c0+ty+8*j)*D + k0+tx] = t32[tx*33 + ty+8*j];
}

// Mp0 chunk: nvec outputs starting at vbase, 8 lanes each
__device__ __forceinline__ void phase_mp0(int vbase, int nvec, int tid,
                                          const float* __restrict__ d1,
                                          const float* __restrict__ d2) {
    int slot = tid >> 3, ch = tid & 7;
    if (slot < nvec) {
        int v = vbase + slot;
        int i = v / N, j = v % N;
        const float4* A = reinterpret_cast<const float4*>(d1 + (size_t)i*D);
        const float4* B = reinterpret_cast<const float4*>(d2 + (size_t)j*D);
        double a0=0,a1=0,a2=0,a3=0;
        #pragma unroll
        for (int t = 0; t < 16; ++t) {
            float4 x = A[ch + 8*t], y = B[ch + 8*t];
            a0 += (double)x.x*(double)y.x; a1 += (double)x.y*(double)y.y;
            a2 += (double)x.z*(double)y.z; a3 += (double)x.w*(double)y.w;
        }
        double s = (a0+a1)+(a2+a3);
        #pragma unroll
        for (int o = 1; o < 8; o <<= 1) s += __shfl_xor(s, o, 64);
        if (ch == 0) g_Mp0[i*N+j] = s;
    }
}

// fused m -> lam -> u -> e -> normalize for (g,row)=gb; 256 threads, 2 cols/thread
__device__ __forceinline__ void phase_mue(int gb, int tid,
                                          const float* __restrict__ d1,
                                          const float* __restrict__ d2,
                                          const float* __restrict__ b, double* smem) {
    double* mp   = smem;          // 80
    double* su   = smem + 80;     // 512
    double* redA = smem + 592;    // 256
    double* redB = smem + 848;    // 256
    int g = gb / N, row = gb % N;
    const float* dsrc = g ? d1 : d2;
    const float* dme  = g ? d2 : d1;
    if (tid < N) mp[tid] = g ? g_Mp0[tid*N + row] : g_Mp0[row*N + tid];
    __syncthreads();

    double m00=0,m01=0,m02=0,m03=0, m10=0,m11=0,m12=0,m13=0;
    #pragma unroll 4
    for (int j = 0; j < N; j += 4) {
        double p0=mp[j], p1=mp[j+1], p2=mp[j+2], p3=mp[j+3];
        m00 += p0*(double)dsrc[(size_t)j*D     + tid];
        m01 += p1*(double)dsrc[(size_t)(j+1)*D + tid];
        m02 += p2*(double)dsrc[(size_t)(j+2)*D + tid];
        m03 += p3*(double)dsrc[(size_t)(j+3)*D + tid];
        m10 += p0*(double)dsrc[(size_t)j*D     + tid+256];
        m11 += p1*(double)dsrc[(size_t)(j+1)*D + tid+256];
        m12 += p2*(double)dsrc[(size_t)(j+2)*D + tid+256];
        m13 += p3*(double)dsrc[(size_t)(j+3)*D + tid+256];
    }
    double mk0=(m00+m01)+(m02+m03), mk1=(m10+m11)+(m12+m13);
    double ak0=(double)dme[(size_t)row*D+tid], ak1=(double)dme[(size_t)row*D+tid+256];

    redA[tid] = ak0*ak0 + ak1*ak1;
    redB[tid] = mk0*mk0 + mk1*mk1;
    __syncthreads();
    for (int o = 128; o > 0; o >>= 1) {
        if (tid < o) { redA[tid] += redA[tid+o]; redB[tid] += redB[tid+o]; }
        __syncthreads();
    }
    double lam = sqrt(redA[0]) / sqrt(redB[0]);
    __syncthreads();
    su[tid] = ak0 + lam*mk0; su[tid+256] = ak1 + lam*mk1;
    __syncthreads();

    const float* wt0 = g_WT + tid;
    const float* wt1 = g_WT + tid + 256;
    double A0=0,A1=0,A2=0,A3=0,A4=0,A5=0,A6=0,A7=0;
    double B0=0,B1=0,B2=0,B3=0,B4=0,B5=0,B6=0,B7=0;
    #pragma unroll 4
    for (int t = 0; t < 64; ++t) {
        int c = t*8;
        A0 += su[c+0]*(double)wt0[(size_t)(c+0)*D];
        A1 += su[c+1]*(double)wt0[(size_t)(c+1)*D];
        A2 += su[c+2]*(double)wt0[(size_t)(c+2)*D];
        A3 += su[c+3]*(double)wt0[(size_t)(c+3)*D];
        A4 += su[c+4]*(double)wt0[(size_t)(c+4)*D];
        A5 += su[c+5]*(double)wt0[(size_t)(c+5)*D];
        A6 += su[c+6]*(double)wt0[(size_t)(c+6)*D];
        A7 += su[c+7]*(double)wt0[(size_t)(c+7)*D];
        B0 += su[c+0]*(double)wt1[(size_t)(c+0)*D];
        B1 += su[c+1]*(double)wt1[(size_t)(c+1)*D];
        B2 += su[c+2]*(double)wt1[(size_t)(c+2)*D];
        B3 += su[c+3]*(double)wt1[(size_t)(c+3)*D];
        B4 += su[c+4]*(double)wt1[(size_t)(c+4)*D];
        B5 += su[c+5]*(double)wt1[(size_t)(c+5)*D];
        B6 += su[c+6]*(double)wt1[(size_t)(c+6)*D];
        B7 += su[c+7]*(double)wt1[(size_t)(c+7)*D];
    }
    double acc0 = (double)b[tid]     + ((A0+A1)+(A2+A3)) + ((A4+A5)+(A6+A7));
    double acc1 = (double)b[tid+256] + ((B0+B1)+(B2+B3)) + ((B4+B5)+(B6+B7));
    double e0 = acc0 > 0.0 ? acc0 : 0.0;
    double e1 = acc1 > 0.0 ? acc1 : 0.0;

    redA[tid] = e0*e0 + e1*e1; __syncthreads();
    for (int o = 128; o > 0; o >>= 1) { if (tid < o) redA[tid] += redA[tid+o]; __syncthreads(); }
    double nrm = sqrt(redA[0]); if (nrm < 1e-12) nrm = 1e-12;
    g_e[g][(size_t)row*D + tid]       = e0 / nrm;
    g_e[g][(size_t)row*D + tid + 256] = e1 / nrm;
}

// P chunk
__device__ __forceinline__ void phase_p(int vbase, int nvec, int tid) {
    int slot = tid >> 3, ch = tid & 7;
    if (slot < nvec) {
        int v = vbase + slot;
        int i1 = v % N, i2 = v / N;
        const double2* a  = reinterpret_cast<const double2*>(g_e[0] + (size_t)i1*D);
        const double2* c2 = reinterpret_cast<const double2*>(g_e[1] + (size_t)i2*D);
        double s0=0,s1=0;
        #pragma unroll
        for (int t = 0; t < 32; ++t) {
            double2 x = a[ch + 8*t], y = c2[ch + 8*t];
            s0 += x.x*y.x; s1 += x.y*y.y;
        }
        double s = s0+s1;
        #pragma unroll
        for (int o = 1; o < 8; o <<= 1) s += __shfl_xor(s, o, 64);
        if (ch == 0) g_P[v] = s;
    }
}

__device__ __forceinline__ double bredux(double v, double* red4, double* sc, int slot, int tid) {
    #pragma unroll
    for (int o = 32; o > 0; o >>= 1) v += __shfl_down(v, o, 64);
    if ((tid & 63) == 0) red4[tid >> 6] = v;
    __syncthreads();
    if (tid == 0) sc[slot] = red4[0] + red4[1] + red4[2] + red4[3];
    __syncthreads();
    return sc[slot];
}

// projected CG + clip + softmax + out; d in registers, p re-read from g_P
__device__ void phase_pcgout(int tid, float* __restrict__ out, double* smem) {
    double* sq  = smem;          // 6400: p, then y, then q, then z/exp
    double* sRy = smem + 6400;   // 80
    double* sCy = smem + 6480;   // 80
    double* red4= smem + 6560;   // 4
    double* sc  = smem + 6564;   // 4
    const double inv80 = 1.0/80.0, inv6400 = 1.0/6400.0, CHI = 1.0/80.0;
    double x[25], r[25], d[25];

    #pragma unroll
    for (int j = 0; j < 25; ++j) { int v = tid + 256*j; sq[v] = g_P[v]; }
    __syncthreads();

    // sums of p
    if (tid < N) {
        double cs = 0.0; const double* dd = sq + tid*N;
        for (int i1 = 0; i1 < N; ++i1) cs += dd[i1];
        sCy[tid] = cs;
    } else if (tid < 2*N) {
        int i1 = tid - N; double rr = 0.0;
        for (int i2 = 0; i2 < N; ++i2) rr += sq[i2*N + i1];
        sRy[i1] = rr;
    }
    __syncthreads();
    if (tid == 0) { double s = 0.0; for (int i = 0; i < N; ++i) s += sCy[i]; sc[0] = s; }
    __syncthreads();
    double Tp = sc[0];
    const double SCALE = 6402.0/160.0;
    double rsp = 0.0;
    #pragma unroll
    for (int j = 0; j < 25; ++j) {
        int v = tid + 256*j; int i1 = v % N, i2 = v / N;
        double rv = SCALE*(sq[v] - sRy[i1]*inv80 - sCy[i2]*inv80 + Tp*inv6400);
        r[j] = rv; d[j] = rv; x[j] = 0.0;
        rsp += rv*rv;
    }
    double rs = bredux(rsp, red4, sc, 2, tid);
    double rs0 = rs;

    for (int it = 0; it < CG_MAX && rs > 1e-22*rs0; ++it) {
        #pragma unroll
        for (int j = 0; j < 25; ++j) { int v = tid + 256*j; sq[v] = g_P[v]*d[j]; }
        __syncthreads();
        if (tid < N) {
            double cs = 0.0; const double* dd = sq + tid*N;
            for (int i1 = 0; i1 < N; ++i1) cs += dd[i1];
            sCy[tid] = cs;
        } else if (tid < 2*N) {
            int i1 = tid - N; double rr = 0.0;
            for (int i2 = 0; i2 < N; ++i2) rr += sq[i2*N + i1];
            sRy[i1] = rr;
        }
        __syncthreads();
        if (tid == 0) { double s = 0.0; for (int i = 0; i < N; ++i) s += sCy[i]; sc[1] = s; }
        __syncthreads();
        double Ty = sc[1];

        double dqp = 0.0;
        #pragma unroll
        for (int j = 0; j < 25; ++j) {
            int v = tid + 256*j; int i1 = v % N, i2 = v / N;
            double qv = CQ*d[j] - (sq[v] - sRy[i1]*inv80 - sCy[i2]*inv80 + Ty*inv6400);
            sq[v] = qv;
            dqp += d[j]*qv;
        }
        double dq = bredux(dqp, red4, sc, 3, tid);
        double alpha = rs / dq;

        double rsnp = 0.0;
        #pragma unroll
        for (int j = 0; j < 25; ++j) {
            int v = tid + 256*j;
            x[j] += alpha*d[j];
            r[j] -= alpha*sq[v];
            rsnp += r[j]*r[j];
        }
        double rsn = bredux(rsnp, red4, sc, 2, tid);
        double beta = rsn / rs;
        rs = rsn;
        #pragma unroll
        for (int j = 0; j < 25; ++j) d[j] = r[j] + beta*d[j];
        __syncthreads();
    }

    #pragma unroll
    for (int j = 0; j < 25; ++j) {
        int v = tid + 256*j;
        double z = CHI + x[j];
        sq[v] = z < 0.0 ? 0.0 : (z > 1.0 ? 1.0 : z);
    }
    __syncthreads();
    if (tid < N) {
        int i1 = tid;
        double mx = -1e300;
        for (int i2 = 0; i2 < N; ++i2) mx = fmax(mx, sq[i2*N + i1]);
        double s = 0.0;
        for (int i2 = 0; i2 < N; ++i2) {
            double e = exp(1000.0*(sq[i2*N + i1] - mx));
            sq[i2*N + i1] = e; s += e;
        }
        double invs = 1.0 / s;
        for (int i2 = 0; i2 < N; ++i2) out[i1*N + i2] = (float)(sq[i2*N + i1] * invs);
    }
}

// ============ cooperative fused kernel ============
__global__ void __launch_bounds__(256,1) k_all(const float* __restrict__ d1,
                                               const float* __restrict__ d2,
                                               const float* __restrict__ W,
                                               const float* __restrict__ b,
                                               float* __restrict__ out) {
    cg::grid_group grid = cg::this_grid();
    __shared__ double smem[SMEM_DBL];
    int bid = blockIdx.x, tid = threadIdx.x;

    phase_wt(bid, tid, W, smem);
    phase_mp0(bid*25, 25, tid, d1, d2);
    grid.sync();
    if (bid < 160) phase_mue(bid, tid, d1, d2, b, smem);
    grid.sync();
    phase_p(bid*25, 25, tid);
    grid.sync();
    if (bid == 0) phase_pcgout(tid, out, smem);
}

// ============ fallback standalone kernels ============
__global__ void __launch_bounds__(256,1) ks_pre(const float* __restrict__ W,
                                                const float* __restrict__ d1,
                                                const float* __restrict__ d2) {
    __shared__ double smem[544];
    int bid = blockIdx.x, tid = threadIdx.x;
    if (bid < 256) phase_wt(bid, tid, W, smem);
    else           phase_mp0((bid-256)*32, 32, tid, d1, d2);
}
__global__ void __launch_bounds__(256,1) ks_mue(const float* __restrict__ d1,
                                                const float* __restrict__ d2,
                                                const float* __restrict__ b) {
    __shared__ double smem[1104];
    phase_mue(blockIdx.x, threadIdx.x, d1, d2, b, smem);
}
__global__ void __launch_bounds__(256,1) ks_p() {
    phase_p(blockIdx.x*32, 32, threadIdx.x);
}
__global__ void __launch_bounds__(256,1) ks_pcgout(float* __restrict__ out) {
    __shared__ double smem[SMEM_DBL];
    phase_pcgout(threadIdx.x, out, smem);
}

extern "C" void kernel_launch(void* const* d_in, const int* in_sizes, int n_in,
                              void* d_out, int out_size, void* d_ws, size_t ws_size,
                              hipStream_t stream) {
    const float* d1 = (const float*)d_in[0];
    const float* d2 = (const float*)d_in[1];
    const float* W  = (const float*)d_in[2];
    const float* b  = (const float*)d_in[3];
    float* out = (float*)d_out;

    void* args[5] = { (void*)&d1, (void*)&d2, (void*)&W, (void*)&b, (void*)&out };
    hipError_t err = hipLaunchCooperativeKernel(reinterpret_cast<void*>(k_all),
                                                dim3(256), dim3(256), args, 0, stream);
    if (err != hipSuccess) {
        ks_pre   <<<dim3(456), dim3(256), 0, stream>>>(W, d1, d2);
        ks_mue   <<<dim3(160), dim3(256), 0, stream>>>(d1, d2, b);
        ks_p     <<<dim3(200), dim3(256), 0, stream>>>();
        ks_pcgout<<<dim3(1),   dim3(256), 0, stream>>>(out);
    }
}

// Round 13
// 227.962 us; speedup vs baseline: 1.6785x; 1.6785x over previous
//
#include <hip/hip_runtime.h>
#include <math.h>

#define N 80
#define D 512
#define NV (N*N)        // 6400
#define CQ 6241.000001  // (n1-1)*(n2-1) + ridge
#define CG_MAX 16
#define SMEM_DBL 6568   // 52,544 B
#define NBLK 256

// ---- static device scratch (inter-phase) ----
__device__ double g_Mp0[N*N];
__device__ float  g_WT[D*D];
__device__ double g_e[2][N*D];
__device__ double g_P[NV];
__device__ unsigned g_cnt;   // returns to 0 after each barrier (replay-safe)
__device__ unsigned g_gen;   // monotonically grows; absolute value unused

// lean grid barrier: sense-reversal on g_gen, device-scope atomics
__device__ __forceinline__ void gbar() {
    __syncthreads();
    if (threadIdx.x == 0) {
        __threadfence();   // release: my writes visible device-wide
        unsigned g = __hip_atomic_load(&g_gen, __ATOMIC_RELAXED, __HIP_MEMORY_SCOPE_AGENT);
        unsigned v = __hip_atomic_fetch_add(&g_cnt, 1, __ATOMIC_ACQ_REL, __HIP_MEMORY_SCOPE_AGENT);
        if (v == NBLK-1) {
            __hip_atomic_store(&g_cnt, 0, __ATOMIC_RELAXED, __HIP_MEMORY_SCOPE_AGENT);
            __hip_atomic_fetch_add(&g_gen, 1, __ATOMIC_RELEASE, __HIP_MEMORY_SCOPE_AGENT);
        } else {
            while (__hip_atomic_load(&g_gen, __ATOMIC_ACQUIRE, __HIP_MEMORY_SCOPE_AGENT) == g)
                __builtin_amdgcn_s_sleep(1);
        }
        __threadfence();   // acquire: others' writes visible to me
    }
    __syncthreads();
}

// ============ phase device functions (verified in R12) ============

__device__ __forceinline__ void phase_wt(int wtb, int tid, const float* __restrict__ W,
                                         double* smem) {
    float* t32 = reinterpret_cast<float*>(smem);       // 32*33 floats
    int c0 = (wtb & 15)*32, k0 = (wtb >> 4)*32;
    int tx = tid & 31, ty = tid >> 5;                  // 32 x 8
    #pragma unroll
    for (int j = 0; j < 4; ++j) t32[(ty+8*j)*33 + tx] = W[(size_t)(k0+ty+8*j)*D + c0+tx];
    __syncthreads();
    #pragma unroll
    for (int j = 0; j < 4; ++j) g_WT[(size_t)(c0+ty+8*j)*D + k0+tx] = t32[tx*33 + ty+8*j];
}

__device__ __forceinline__ void phase_mp0(int vbase, int nvec, int tid,
                                          const float* __restrict__ d1,
                                          const float* __restrict__ d2) {
    int slot = tid >> 3, ch = tid & 7;
    if (slot < nvec) {
        int v = vbase + slot;
        int i = v / N, j = v % N;
        const float4* A = reinterpret_cast<const float4*>(d1 + (size_t)i*D);
        const float4* B = reinterpret_cast<const float4*>(d2 + (size_t)j*D);
        double a0=0,a1=0,a2=0,a3=0;
        #pragma unroll
        for (int t = 0; t < 16; ++t) {
            float4 x = A[ch + 8*t], y = B[ch + 8*t];
            a0 += (double)x.x*(double)y.x; a1 += (double)x.y*(double)y.y;
            a2 += (double)x.z*(double)y.z; a3 += (double)x.w*(double)y.w;
        }
        double s = (a0+a1)+(a2+a3);
        #pragma unroll
        for (int o = 1; o < 8; o <<= 1) s += __shfl_xor(s, o, 64);
        if (ch == 0) g_Mp0[i*N+j] = s;
    }
}

__device__ __forceinline__ void phase_mue(int gb, int tid,
                                          const float* __restrict__ d1,
                                          const float* __restrict__ d2,
                                          const float* __restrict__ b, double* smem) {
    double* mp   = smem;          // 80
    double* su   = smem + 80;     // 512
    double* redA = smem + 592;    // 256
    double* redB = smem + 848;    // 256
    int g = gb / N, row = gb % N;
    const float* dsrc = g ? d1 : d2;
    const float* dme  = g ? d2 : d1;
    if (tid < N) mp[tid] = g ? g_Mp0[tid*N + row] : g_Mp0[row*N + tid];
    __syncthreads();

    double m00=0,m01=0,m02=0,m03=0, m10=0,m11=0,m12=0,m13=0;
    #pragma unroll 4
    for (int j = 0; j < N; j += 4) {
        double p0=mp[j], p1=mp[j+1], p2=mp[j+2], p3=mp[j+3];
        m00 += p0*(double)dsrc[(size_t)j*D     + tid];
        m01 += p1*(double)dsrc[(size_t)(j+1)*D + tid];
        m02 += p2*(double)dsrc[(size_t)(j+2)*D + tid];
        m03 += p3*(double)dsrc[(size_t)(j+3)*D + tid];
        m10 += p0*(double)dsrc[(size_t)j*D     + tid+256];
        m11 += p1*(double)dsrc[(size_t)(j+1)*D + tid+256];
        m12 += p2*(double)dsrc[(size_t)(j+2)*D + tid+256];
        m13 += p3*(double)dsrc[(size_t)(j+3)*D + tid+256];
    }
    double mk0=(m00+m01)+(m02+m03), mk1=(m10+m11)+(m12+m13);
    double ak0=(double)dme[(size_t)row*D+tid], ak1=(double)dme[(size_t)row*D+tid+256];

    redA[tid] = ak0*ak0 + ak1*ak1;
    redB[tid] = mk0*mk0 + mk1*mk1;
    __syncthreads();
    for (int o = 128; o > 0; o >>= 1) {
        if (tid < o) { redA[tid] += redA[tid+o]; redB[tid] += redB[tid+o]; }
        __syncthreads();
    }
    double lam = sqrt(redA[0]) / sqrt(redB[0]);
    __syncthreads();
    su[tid] = ak0 + lam*mk0; su[tid+256] = ak1 + lam*mk1;
    __syncthreads();

    const float* wt0 = g_WT + tid;
    const float* wt1 = g_WT + tid + 256;
    double A0=0,A1=0,A2=0,A3=0,A4=0,A5=0,A6=0,A7=0;
    double B0=0,B1=0,B2=0,B3=0,B4=0,B5=0,B6=0,B7=0;
    #pragma unroll 4
    for (int t = 0; t < 64; ++t) {
        int c = t*8;
        A0 += su[c+0]*(double)wt0[(size_t)(c+0)*D];
        A1 += su[c+1]*(double)wt0[(size_t)(c+1)*D];
        A2 += su[c+2]*(double)wt0[(size_t)(c+2)*D];
        A3 += su[c+3]*(double)wt0[(size_t)(c+3)*D];
        A4 += su[c+4]*(double)wt0[(size_t)(c+4)*D];
        A5 += su[c+5]*(double)wt0[(size_t)(c+5)*D];
        A6 += su[c+6]*(double)wt0[(size_t)(c+6)*D];
        A7 += su[c+7]*(double)wt0[(size_t)(c+7)*D];
        B0 += su[c+0]*(double)wt1[(size_t)(c+0)*D];
        B1 += su[c+1]*(double)wt1[(size_t)(c+1)*D];
        B2 += su[c+2]*(double)wt1[(size_t)(c+2)*D];
        B3 += su[c+3]*(double)wt1[(size_t)(c+3)*D];
        B4 += su[c+4]*(double)wt1[(size_t)(c+4)*D];
        B5 += su[c+5]*(double)wt1[(size_t)(c+5)*D];
        B6 += su[c+6]*(double)wt1[(size_t)(c+6)*D];
        B7 += su[c+7]*(double)wt1[(size_t)(c+7)*D];
    }
    double acc0 = (double)b[tid]     + ((A0+A1)+(A2+A3)) + ((A4+A5)+(A6+A7));
    double acc1 = (double)b[tid+256] + ((B0+B1)+(B2+B3)) + ((B4+B5)+(B6+B7));
    double e0 = acc0 > 0.0 ? acc0 : 0.0;
    double e1 = acc1 > 0.0 ? acc1 : 0.0;

    redA[tid] = e0*e0 + e1*e1; __syncthreads();
    for (int o = 128; o > 0; o >>= 1) { if (tid < o) redA[tid] += redA[tid+o]; __syncthreads(); }
    double nrm = sqrt(redA[0]); if (nrm < 1e-12) nrm = 1e-12;
    g_e[g][(size_t)row*D + tid]       = e0 / nrm;
    g_e[g][(size_t)row*D + tid + 256] = e1 / nrm;
}

__device__ __forceinline__ void phase_p(int vbase, int nvec, int tid) {
    int slot = tid >> 3, ch = tid & 7;
    if (slot < nvec) {
        int v = vbase + slot;
        int i1 = v % N, i2 = v / N;
        const double2* a  = reinterpret_cast<const double2*>(g_e[0] + (size_t)i1*D);
        const double2* c2 = reinterpret_cast<const double2*>(g_e[1] + (size_t)i2*D);
        double s0=0,s1=0;
        #pragma unroll
        for (int t = 0; t < 32; ++t) {
            double2 x = a[ch + 8*t], y = c2[ch + 8*t];
            s0 += x.x*y.x; s1 += x.y*y.y;
        }
        double s = s0+s1;
        #pragma unroll
        for (int o = 1; o < 8; o <<= 1) s += __shfl_xor(s, o, 64);
        if (ch == 0) g_P[v] = s;
    }
}

__device__ __forceinline__ double bredux(double v, double* red4, double* sc, int slot, int tid) {
    #pragma unroll
    for (int o = 32; o > 0; o >>= 1) v += __shfl_down(v, o, 64);
    if ((tid & 63) == 0) red4[tid >> 6] = v;
    __syncthreads();
    if (tid == 0) sc[slot] = red4[0] + red4[1] + red4[2] + red4[3];
    __syncthreads();
    return sc[slot];
}

__device__ void phase_pcgout(int tid, float* __restrict__ out, double* smem) {
    double* sq  = smem;          // 6400
    double* sRy = smem + 6400;   // 80
    double* sCy = smem + 6480;   // 80
    double* red4= smem + 6560;   // 4
    double* sc  = smem + 6564;   // 4
    const double inv80 = 1.0/80.0, inv6400 = 1.0/6400.0, CHI = 1.0/80.0;
    double x[25], r[25], d[25];

    #pragma unroll
    for (int j = 0; j < 25; ++j) { int v = tid + 256*j; sq[v] = g_P[v]; }
    __syncthreads();

    if (tid < N) {
        double cs = 0.0; const double* dd = sq + tid*N;
        for (int i1 = 0; i1 < N; ++i1) cs += dd[i1];
        sCy[tid] = cs;
    } else if (tid < 2*N) {
        int i1 = tid - N; double rr = 0.0;
        for (int i2 = 0; i2 < N; ++i2) rr += sq[i2*N + i1];
        sRy[i1] = rr;
    }
    __syncthreads();
    if (tid == 0) { double s = 0.0; for (int i = 0; i < N; ++i) s += sCy[i]; sc[0] = s; }
    __syncthreads();
    double Tp = sc[0];
    const double SCALE = 6402.0/160.0;
    double rsp = 0.0;
    #pragma unroll
    for (int j = 0; j < 25; ++j) {
        int v = tid + 256*j; int i1 = v % N, i2 = v / N;
        double rv = SCALE*(sq[v] - sRy[i1]*inv80 - sCy[i2]*inv80 + Tp*inv6400);
        r[j] = rv; d[j] = rv; x[j] = 0.0;
        rsp += rv*rv;
    }
    double rs = bredux(rsp, red4, sc, 2, tid);
    double rs0 = rs;

    for (int it = 0; it < CG_MAX && rs > 1e-22*rs0; ++it) {
        #pragma unroll
        for (int j = 0; j < 25; ++j) { int v = tid + 256*j; sq[v] = g_P[v]*d[j]; }
        __syncthreads();
        if (tid < N) {
            double cs = 0.0; const double* dd = sq + tid*N;
            for (int i1 = 0; i1 < N; ++i1) cs += dd[i1];
            sCy[tid] = cs;
        } else if (tid < 2*N) {
            int i1 = tid - N; double rr = 0.0;
            for (int i2 = 0; i2 < N; ++i2) rr += sq[i2*N + i1];
            sRy[i1] = rr;
        }
        __syncthreads();
        if (tid == 0) { double s = 0.0; for (int i = 0; i < N; ++i) s += sCy[i]; sc[1] = s; }
        __syncthreads();
        double Ty = sc[1];

        double dqp = 0.0;
        #pragma unroll
        for (int j = 0; j < 25; ++j) {
            int v = tid + 256*j; int i1 = v % N, i2 = v / N;
            double qv = CQ*d[j] - (sq[v] - sRy[i1]*inv80 - sCy[i2]*inv80 + Ty*inv6400);
            sq[v] = qv;
            dqp += d[j]*qv;
        }
        double dq = bredux(dqp, red4, sc, 3, tid);
        double alpha = rs / dq;

        double rsnp = 0.0;
        #pragma unroll
        for (int j = 0; j < 25; ++j) {
            int v = tid + 256*j;
            x[j] += alpha*d[j];
            r[j] -= alpha*sq[v];
            rsnp += r[j]*r[j];
        }
        double rsn = bredux(rsnp, red4, sc, 2, tid);
        double beta = rsn / rs;
        rs = rsn;
        #pragma unroll
        for (int j = 0; j < 25; ++j) d[j] = r[j] + beta*d[j];
        __syncthreads();
    }

    #pragma unroll
    for (int j = 0; j < 25; ++j) {
        int v = tid + 256*j;
        double z = CHI + x[j];
        sq[v] = z < 0.0 ? 0.0 : (z > 1.0 ? 1.0 : z);
    }
    __syncthreads();
    if (tid < N) {
        int i1 = tid;
        double mx = -1e300;
        for (int i2 = 0; i2 < N; ++i2) mx = fmax(mx, sq[i2*N + i1]);
        double s = 0.0;
        for (int i2 = 0; i2 < N; ++i2) {
            double e = exp(1000.0*(sq[i2*N + i1] - mx));
            sq[i2*N + i1] = e; s += e;
        }
        double invs = 1.0 / s;
        for (int i2 = 0; i2 < N; ++i2) out[i1*N + i2] = (float)(sq[i2*N + i1] * invs);
    }
}

// ============ fully fused kernel with lean device barrier ============
__global__ void __launch_bounds__(256,1) k_all(const float* __restrict__ d1,
                                               const float* __restrict__ d2,
                                               const float* __restrict__ W,
                                               const float* __restrict__ b,
                                               float* __restrict__ out) {
    __shared__ double smem[SMEM_DBL];
    int bid = blockIdx.x, tid = threadIdx.x;

    phase_wt(bid, tid, W, smem);
    phase_mp0(bid*25, 25, tid, d1, d2);
    gbar();
    if (bid < 160) phase_mue(bid, tid, d1, d2, b, smem);
    gbar();
    phase_p(bid*25, 25, tid);
    gbar();
    if (bid == 0) phase_pcgout(tid, out, smem);
}

extern "C" void kernel_launch(void* const* d_in, const int* in_sizes, int n_in,
                              void* d_out, int out_size, void* d_ws, size_t ws_size,
                              hipStream_t stream) {
    const float* d1 = (const float*)d_in[0];
    const float* d2 = (const float*)d_in[1];
    const float* W  = (const float*)d_in[2];
    const float* b  = (const float*)d_in[3];
    float* out = (float*)d_out;

    k_all<<<dim3(NBLK), dim3(256), 0, stream>>>(d1, d2, W, b, out);
}

// Round 14
// 135.112 us; speedup vs baseline: 2.8319x; 1.6872x over previous
//
#include <hip/hip_runtime.h>
#include <math.h>

#define N 80
#define D 512
#define NV (N*N)        // 6400
#define CQ 6241.000001  // (n1-1)*(n2-1) + ridge
#define NEU_K 4         // Neumann terms beyond the first (each gains ~3.8 digits)
#define NBLK 160
#define SMEM_DBL 6568   // 52,544 B

// ---- inter-phase scratch ----
__device__ double g_e[2][N*D];
__device__ double g_P[NV];
__device__ unsigned g_cnt1, g_gen1;   // full barrier (cnt self-resets; gen monotonic)
__device__ unsigned g_cnt2;           // phase-C completion count (block 0 resets)

__device__ __forceinline__ double wred64(double s) {
    #pragma unroll
    for (int o = 1; o < 64; o <<= 1) s += __shfl_xor(s, o, 64);
    return s;
}

// full grid barrier, cache-quiet polling (RELAXED; ACQUIRE every 256 polls + at exit)
__device__ __forceinline__ void fullbar() {
    __syncthreads();
    if (threadIdx.x == 0) {
        unsigned g = __hip_atomic_load(&g_gen1, __ATOMIC_RELAXED, __HIP_MEMORY_SCOPE_AGENT);
        unsigned v = __hip_atomic_fetch_add(&g_cnt1, 1, __ATOMIC_ACQ_REL, __HIP_MEMORY_SCOPE_AGENT);
        if (v == NBLK-1) {
            __hip_atomic_store(&g_cnt1, 0, __ATOMIC_RELAXED, __HIP_MEMORY_SCOPE_AGENT);
            __hip_atomic_fetch_add(&g_gen1, 1, __ATOMIC_RELEASE, __HIP_MEMORY_SCOPE_AGENT);
        } else {
            int it = 0;
            for (;;) {
                unsigned cur = ((++it & 255) == 0)
                    ? __hip_atomic_load(&g_gen1, __ATOMIC_ACQUIRE, __HIP_MEMORY_SCOPE_AGENT)
                    : __hip_atomic_load(&g_gen1, __ATOMIC_RELAXED, __HIP_MEMORY_SCOPE_AGENT);
                if (cur != g) break;
                __builtin_amdgcn_s_sleep(2);
            }
        }
        (void)__hip_atomic_load(&g_gen1, __ATOMIC_ACQUIRE, __HIP_MEMORY_SCOPE_AGENT);
    }
    __syncthreads();
}

__global__ void __launch_bounds__(256,1) k_all(const float* __restrict__ d1,
                                               const float* __restrict__ d2,
                                               const float* __restrict__ W,
                                               const float* __restrict__ b,
                                               float* __restrict__ out) {
    __shared__ double smem[SMEM_DBL];
    int bid = blockIdx.x, tid = threadIdx.x;
    int wv = tid >> 6, ln = tid & 63;

    // ========== phase AB: local Mp0 row/col -> lam -> u -> GEMM -> norm ==========
    {
        double* su   = smem;          // 512 (u)
        double* es   = smem + 512;    // 512 (raw e)
        double* mp   = smem + 1024;   // 80
        double* redA = smem + 1104;   // 256
        double* redB = smem + 1360;   // 256

        int g = bid / N, row = bid % N;
        const float* dme  = g ? d2 : d1;    // own data row
        const float* dsrc = g ? d1 : d2;    // other graph (summed)

        // own row into registers: a_reg[q] = dme[row][ln+64q]
        double a_reg[8];
        #pragma unroll
        for (int q = 0; q < 8; ++q) a_reg[q] = (double)dme[(size_t)row*D + ln + 64*q];

        // mp[j] = dot(dme[row], dsrc[j]); wave wv handles j = wv*20..wv*20+19
        for (int t = 0; t < 20; ++t) {
            int j = wv*20 + t;
            const float* R = dsrc + (size_t)j*D;
            double s = 0.0;
            #pragma unroll
            for (int q = 0; q < 8; ++q) s += a_reg[q] * (double)R[ln + 64*q];
            s = wred64(s);
            if (ln == 0) mp[j] = s;
        }
        __syncthreads();

        // m_k for k=tid, tid+256
        double m00=0,m01=0, m10=0,m11=0;
        #pragma unroll 4
        for (int j = 0; j < N; j += 2) {
            double p0 = mp[j], p1 = mp[j+1];
            m00 += p0*(double)dsrc[(size_t)j*D     + tid];
            m01 += p1*(double)dsrc[(size_t)(j+1)*D + tid];
            m10 += p0*(double)dsrc[(size_t)j*D     + tid+256];
            m11 += p1*(double)dsrc[(size_t)(j+1)*D + tid+256];
        }
        double mk0 = m00+m01, mk1 = m10+m11;
        double ak0 = (double)dme[(size_t)row*D + tid];
        double ak1 = (double)dme[(size_t)row*D + tid + 256];

        redA[tid] = ak0*ak0 + ak1*ak1;
        redB[tid] = mk0*mk0 + mk1*mk1;
        __syncthreads();
        for (int o = 128; o > 0; o >>= 1) {
            if (tid < o) { redA[tid] += redA[tid+o]; redB[tid] += redB[tid+o]; }
            __syncthreads();
        }
        double lam = sqrt(redA[0]) / sqrt(redB[0]);
        __syncthreads();
        su[tid] = ak0 + lam*mk0; su[tid+256] = ak1 + lam*mk1;
        __syncthreads();

        // redistribute u to registers: u_reg[q] = su[ln+64q]
        double u_reg[8];
        #pragma unroll
        for (int q = 0; q < 8; ++q) u_reg[q] = su[ln + 64*q];

        // GEMM: wave wv handles rows k = wv*128 + t; coalesced W row reads, no LDS
        for (int t = 0; t < 128; ++t) {
            int k = wv*128 + t;
            const float* Wr = W + (size_t)k*D;
            double s = 0.0;
            #pragma unroll
            for (int q = 0; q < 8; ++q) s += u_reg[q] * (double)Wr[ln + 64*q];
            s = wred64(s);
            if (ln == 0) { double a = (double)b[k] + s; es[k] = a > 0.0 ? a : 0.0; }
        }
        __syncthreads();

        redA[tid] = es[tid]*es[tid] + es[tid+256]*es[tid+256];
        __syncthreads();
        for (int o = 128; o > 0; o >>= 1) { if (tid < o) redA[tid] += redA[tid+o]; __syncthreads(); }
        double nrm = sqrt(redA[0]); if (nrm < 1e-12) nrm = 1e-12;
        double inv = 1.0 / nrm;
        g_e[g][(size_t)row*D + tid]       = es[tid]*inv;
        g_e[g][(size_t)row*D + tid + 256] = es[tid+256]*inv;
    }

    fullbar();   // all e visible

    // ========== phase C: P, 40 outputs/block ==========
    {
        int slot = tid >> 3, ch = tid & 7;
        for (int s8 = slot; s8 < 40; s8 += 32) {
            int v = bid*40 + s8;
            int i1 = v % N, i2 = v / N;
            const double2* a  = reinterpret_cast<const double2*>(g_e[0] + (size_t)i1*D);
            const double2* c2 = reinterpret_cast<const double2*>(g_e[1] + (size_t)i2*D);
            double s0=0,s1=0;
            #pragma unroll
            for (int t = 0; t < 32; ++t) {
                double2 x = a[ch + 8*t], y = c2[ch + 8*t];
                s0 += x.x*y.x; s1 += x.y*y.y;
            }
            double s = s0+s1;
            #pragma unroll
            for (int o = 1; o < 8; o <<= 1) s += __shfl_xor(s, o, 64);
            if (ch == 0) g_P[v] = s;
        }
    }
    __syncthreads();
    if (tid == 0) __hip_atomic_fetch_add(&g_cnt2, 1, __ATOMIC_RELEASE, __HIP_MEMORY_SCOPE_AGENT);
    if (bid != 0) return;   // signal-and-exit: no spinning blocks

    // ========== phase D (block 0): Neumann solve + clip + softmax + out ==========
    if (tid == 0) {
        int it = 0;
        for (;;) {
            unsigned c = ((++it & 255) == 0)
                ? __hip_atomic_load(&g_cnt2, __ATOMIC_ACQUIRE, __HIP_MEMORY_SCOPE_AGENT)
                : __hip_atomic_load(&g_cnt2, __ATOMIC_RELAXED, __HIP_MEMORY_SCOPE_AGENT);
            if (c >= NBLK) break;
            __builtin_amdgcn_s_sleep(2);
        }
        __hip_atomic_store(&g_cnt2, 0, __ATOMIC_RELAXED, __HIP_MEMORY_SCOPE_AGENT);
        (void)__hip_atomic_load(&g_cnt2, __ATOMIC_ACQUIRE, __HIP_MEMORY_SCOPE_AGENT);
    }
    __syncthreads();

    {
        double* sv  = smem;          // 6400
        double* sR  = smem + 6400;   // 80  (R[i1])
        double* sC  = smem + 6480;   // 80  (C[i2])
        double* ssc = smem + 6560;   // 8
        const double inv80 = 1.0/80.0, inv6400 = 1.0/6400.0, CHI = 1.0/80.0;
        const double invCQ = 1.0/CQ;
        double ploc[25], vv[25], x[25];

        #pragma unroll
        for (int j = 0; j < 25; ++j) { int v = tid + 256*j; ploc[j] = g_P[v]; sv[v] = ploc[j]; }
        __syncthreads();

        // sums of p
        if (tid < N) {                       // i2 = tid: contiguous
            double cs = 0.0; const double* dd = sv + tid*N;
            for (int i1 = 0; i1 < N; ++i1) cs += dd[i1];
            sC[tid] = cs;
        } else if (tid < 2*N) {              // i1 = tid-N: stride N
            int i1 = tid - N; double rr = 0.0;
            for (int i2 = 0; i2 < N; ++i2) rr += sv[i2*N + i1];
            sR[i1] = rr;
        }
        __syncthreads();
        if (tid == 0) { double s = 0.0; for (int i = 0; i < N; ++i) s += sC[i]; ssc[0] = s; }
        __syncthreads();
        double Tp = ssc[0];
        const double SCALE = 6402.0/160.0;
        #pragma unroll
        for (int j = 0; j < 25; ++j) {
            int v = tid + 256*j; int i1 = v % N, i2 = v / N;
            double rv = SCALE*(ploc[j] - sR[i1]*inv80 - sC[i2]*inv80 + Tp*inv6400);
            vv[j] = rv;
            x[j]  = rv*invCQ;
        }
        __syncthreads();

        // Neumann: v <- M(v)/CQ = P(p.*v)/CQ ; x += v/CQ   (K fixed terms)
        for (int k = 0; k < NEU_K; ++k) {
            #pragma unroll
            for (int j = 0; j < 25; ++j) { int v = tid + 256*j; sv[v] = ploc[j]*vv[j]; }
            __syncthreads();
            if (tid < N) {
                double cs = 0.0; const double* dd = sv + tid*N;
                for (int i1 = 0; i1 < N; ++i1) cs += dd[i1];
                sC[tid] = cs;
            } else if (tid < 2*N) {
                int i1 = tid - N; double rr = 0.0;
                for (int i2 = 0; i2 < N; ++i2) rr += sv[i2*N + i1];
                sR[i1] = rr;
            }
            __syncthreads();
            if (tid == 0) { double s = 0.0; for (int i = 0; i < N; ++i) s += sC[i]; ssc[1] = s; }
            __syncthreads();
            double Ty = ssc[1];
            #pragma unroll
            for (int j = 0; j < 25; ++j) {
                int v = tid + 256*j; int i1 = v % N, i2 = v / N;
                double mv = ploc[j]*vv[j] - sR[i1]*inv80 - sC[i2]*inv80 + Ty*inv6400;
                vv[j] = mv*invCQ;
                x[j] += vv[j]*invCQ;
            }
            __syncthreads();
        }

        // z = clip(1/80 + x); softmax(1000 z) over i2 per i1
        #pragma unroll
        for (int j = 0; j < 25; ++j) {
            int v = tid + 256*j;
            double z = CHI + x[j];
            sv[v] = z < 0.0 ? 0.0 : (z > 1.0 ? 1.0 : z);
        }
        __syncthreads();
        if (tid < N) {                        // max over i2 for column i1=tid
            double mx = -1e300;
            for (int i2 = 0; i2 < N; ++i2) mx = fmax(mx, sv[i2*N + tid]);
            sR[tid] = mx;
        }
        __syncthreads();
        #pragma unroll
        for (int j = 0; j < 25; ++j) {
            int v = tid + 256*j; int i1 = v % N;
            sv[v] = exp(1000.0*(sv[v] - sR[i1]));
        }
        __syncthreads();
        if (tid < N) {
            double s = 0.0;
            for (int i2 = 0; i2 < N; ++i2) s += sv[i2*N + tid];
            sC[tid] = 1.0 / s;
        }
        __syncthreads();
        #pragma unroll
        for (int j = 0; j < 25; ++j) {
            int v = tid + 256*j; int i1 = v % N, i2 = v / N;
            out[i1*N + i2] = (float)(sv[v] * sC[i1]);
        }
    }
}

extern "C" void kernel_launch(void* const* d_in, const int* in_sizes, int n_in,
                              void* d_out, int out_size, void* d_ws, size_t ws_size,
                              hipStream_t stream) {
    const float* d1 = (const float*)d_in[0];
    const float* d2 = (const float*)d_in[1];
    const float* W  = (const float*)d_in[2];
    const float* b  = (const float*)d_in[3];
    float* out = (float*)d_out;

    k_all<<<dim3(NBLK), dim3(256), 0, stream>>>(d1, d2, W, b, out);
}

// Round 15
// 113.121 us; speedup vs baseline: 3.3825x; 1.1944x over previous
//
#include <hip/hip_runtime.h>
#include <math.h>

#define N 80
#define D 512
#define NV (N*N)        // 6400
#define CQ 6241.000001  // (n1-1)*(n2-1) + ridge
#define NEU_K 4         // Neumann terms beyond the first (~3.8 digits/term)

// ---- inter-kernel scratch ----
__device__ double g_e[2][N*D];
__device__ double g_P[NV];

__device__ __forceinline__ double wred64(double s) {
    #pragma unroll
    for (int o = 1; o < 64; o <<= 1) s += __shfl_xor(s, o, 64);
    return s;
}

// fused: local Mp0 row/col -> lam -> u -> GEMM(W untransposed) -> row-normalize
// one block per (g,row), 256 threads (4 waves)
__global__ void __launch_bounds__(256,1) ks_mue(const float* __restrict__ d1,
                                                const float* __restrict__ d2,
                                                const float* __restrict__ W,
                                                const float* __restrict__ b) {
    __shared__ double su[D];
    __shared__ double es[D];
    __shared__ double mp[N];
    __shared__ double redA[256], redB[256];
    int bid = blockIdx.x, tid = threadIdx.x;
    int wv = tid >> 6, ln = tid & 63;

    int g = bid / N, row = bid % N;
    const float* dme  = g ? d2 : d1;    // own data row
    const float* dsrc = g ? d1 : d2;    // other graph (summed)

    // own row into registers
    double a_reg[8];
    #pragma unroll
    for (int q = 0; q < 8; ++q) a_reg[q] = (double)dme[(size_t)row*D + ln + 64*q];

    // mp[j] = dot(dme[row], dsrc[j]); wave wv handles 20 j's
    for (int t = 0; t < 20; ++t) {
        int j = wv*20 + t;
        const float* R = dsrc + (size_t)j*D;
        double s = 0.0;
        #pragma unroll
        for (int q = 0; q < 8; ++q) s += a_reg[q] * (double)R[ln + 64*q];
        s = wred64(s);
        if (ln == 0) mp[j] = s;
    }
    __syncthreads();

    // m_k for k=tid, tid+256
    double m00=0,m01=0, m10=0,m11=0;
    #pragma unroll 4
    for (int j = 0; j < N; j += 2) {
        double p0 = mp[j], p1 = mp[j+1];
        m00 += p0*(double)dsrc[(size_t)j*D     + tid];
        m01 += p1*(double)dsrc[(size_t)(j+1)*D + tid];
        m10 += p0*(double)dsrc[(size_t)j*D     + tid+256];
        m11 += p1*(double)dsrc[(size_t)(j+1)*D + tid+256];
    }
    double mk0 = m00+m01, mk1 = m10+m11;
    double ak0 = (double)dme[(size_t)row*D + tid];
    double ak1 = (double)dme[(size_t)row*D + tid + 256];

    redA[tid] = ak0*ak0 + ak1*ak1;
    redB[tid] = mk0*mk0 + mk1*mk1;
    __syncthreads();
    for (int o = 128; o > 0; o >>= 1) {
        if (tid < o) { redA[tid] += redA[tid+o]; redB[tid] += redB[tid+o]; }
        __syncthreads();
    }
    double lam = sqrt(redA[0]) / sqrt(redB[0]);
    __syncthreads();
    su[tid] = ak0 + lam*mk0; su[tid+256] = ak1 + lam*mk1;
    __syncthreads();

    // u to registers
    double u_reg[8];
    #pragma unroll
    for (int q = 0; q < 8; ++q) u_reg[q] = su[ln + 64*q];

    // GEMM: wave wv handles rows k = wv*128 + t (coalesced W row reads)
    for (int t = 0; t < 128; ++t) {
        int k = wv*128 + t;
        const float* Wr = W + (size_t)k*D;
        double s = 0.0;
        #pragma unroll
        for (int q = 0; q < 8; ++q) s += u_reg[q] * (double)Wr[ln + 64*q];
        s = wred64(s);
        if (ln == 0) { double a = (double)b[k] + s; es[k] = a > 0.0 ? a : 0.0; }
    }
    __syncthreads();

    redA[tid] = es[tid]*es[tid] + es[tid+256]*es[tid+256];
    __syncthreads();
    for (int o = 128; o > 0; o >>= 1) { if (tid < o) redA[tid] += redA[tid+o]; __syncthreads(); }
    double nrm = sqrt(redA[0]); if (nrm < 1e-12) nrm = 1e-12;
    double inv = 1.0 / nrm;
    g_e[g][(size_t)row*D + tid]       = es[tid]*inv;
    g_e[g][(size_t)row*D + tid + 256] = es[tid+256]*inv;
}

// P[v] = e1n[i1] . e2n[i2] ; 8 lanes/output, double2-interleaved
__global__ void __launch_bounds__(256,1) ks_p() {
    int gidx = blockIdx.x*256 + threadIdx.x;      // 51200 threads
    int v = gidx >> 3, ch = gidx & 7;
    int i1 = v % N, i2 = v / N;
    const double2* a  = reinterpret_cast<const double2*>(g_e[0] + (size_t)i1*D);
    const double2* c2 = reinterpret_cast<const double2*>(g_e[1] + (size_t)i2*D);
    double s0=0,s1=0;
    #pragma unroll
    for (int t = 0; t < 32; ++t) {
        double2 x = a[ch + 8*t], y = c2[ch + 8*t];
        s0 += x.x*y.x; s1 += x.y*y.y;
    }
    double s = s0+s1;
    #pragma unroll
    for (int o = 1; o < 8; o <<= 1) s += __shfl_xor(s, o, 64);
    if (ch == 0) g_P[v] = s;
}

// Neumann solve on null(A) + clip + softmax + out; single block
//   r0 = (6402/160) P(p);  x = sum_k M^k r0 / CQ^{k+1},  M(v) = P(p.*v)
__global__ void __launch_bounds__(256,1) ks_out(float* __restrict__ out) {
    __shared__ double sv[NV];
    __shared__ double sR[N], sC[N];
    __shared__ double ssc[4];
    const double inv80 = 1.0/80.0, inv6400 = 1.0/6400.0, CHI = 1.0/80.0;
    const double invCQ = 1.0/CQ;
    int tid = threadIdx.x;
    double ploc[25], vv[25], x[25];

    #pragma unroll
    for (int j = 0; j < 25; ++j) { int v = tid + 256*j; ploc[j] = g_P[v]; sv[v] = ploc[j]; }
    __syncthreads();

    if (tid < N) {
        double cs = 0.0; const double* dd = sv + tid*N;
        for (int i1 = 0; i1 < N; ++i1) cs += dd[i1];
        sC[tid] = cs;
    } else if (tid < 2*N) {
        int i1 = tid - N; double rr = 0.0;
        for (int i2 = 0; i2 < N; ++i2) rr += sv[i2*N + i1];
        sR[i1] = rr;
    }
    __syncthreads();
    if (tid == 0) { double s = 0.0; for (int i = 0; i < N; ++i) s += sC[i]; ssc[0] = s; }
    __syncthreads();
    double Tp = ssc[0];
    const double SCALE = 6402.0/160.0;
    #pragma unroll
    for (int j = 0; j < 25; ++j) {
        int v = tid + 256*j; int i1 = v % N, i2 = v / N;
        double rv = SCALE*(ploc[j] - sR[i1]*inv80 - sC[i2]*inv80 + Tp*inv6400);
        vv[j] = rv;
        x[j]  = rv*invCQ;
    }
    __syncthreads();

    for (int k = 0; k < NEU_K; ++k) {
        #pragma unroll
        for (int j = 0; j < 25; ++j) { int v = tid + 256*j; sv[v] = ploc[j]*vv[j]; }
        __syncthreads();
        if (tid < N) {
            double cs = 0.0; const double* dd = sv + tid*N;
            for (int i1 = 0; i1 < N; ++i1) cs += dd[i1];
            sC[tid] = cs;
        } else if (tid < 2*N) {
            int i1 = tid - N; double rr = 0.0;
            for (int i2 = 0; i2 < N; ++i2) rr += sv[i2*N + i1];
            sR[i1] = rr;
        }
        __syncthreads();
        if (tid == 0) { double s = 0.0; for (int i = 0; i < N; ++i) s += sC[i]; ssc[1] = s; }
        __syncthreads();
        double Ty = ssc[1];
        #pragma unroll
        for (int j = 0; j < 25; ++j) {
            int v = tid + 256*j; int i1 = v % N, i2 = v / N;
            double mv = ploc[j]*vv[j] - sR[i1]*inv80 - sC[i2]*inv80 + Ty*inv6400;
            vv[j] = mv*invCQ;
            x[j] += vv[j]*invCQ;
        }
        __syncthreads();
    }

    #pragma unroll
    for (int j = 0; j < 25; ++j) {
        int v = tid + 256*j;
        double z = CHI + x[j];
        sv[v] = z < 0.0 ? 0.0 : (z > 1.0 ? 1.0 : z);
    }
    __syncthreads();
    if (tid < N) {
        double mx = -1e300;
        for (int i2 = 0; i2 < N; ++i2) mx = fmax(mx, sv[i2*N + tid]);
        sR[tid] = mx;
    }
    __syncthreads();
    #pragma unroll
    for (int j = 0; j < 25; ++j) {
        int v = tid + 256*j; int i1 = v % N;
        sv[v] = exp(1000.0*(sv[v] - sR[i1]));
    }
    __syncthreads();
    if (tid < N) {
        double s = 0.0;
        for (int i2 = 0; i2 < N; ++i2) s += sv[i2*N + tid];
        sC[tid] = 1.0 / s;
    }
    __syncthreads();
    #pragma unroll
    for (int j = 0; j < 25; ++j) {
        int v = tid + 256*j; int i1 = v % N, i2 = v / N;
        out[i1*N + i2] = (float)(sv[v] * sC[i1]);
    }
}

extern "C" void kernel_launch(void* const* d_in, const int* in_sizes, int n_in,
                              void* d_out, int out_size, void* d_ws, size_t ws_size,
                              hipStream_t stream) {
    const float* d1 = (const float*)d_in[0];
    const float* d2 = (const float*)d_in[1];
    const float* W  = (const float*)d_in[2];
    const float* b  = (const float*)d_in[3];
    float* out = (float*)d_out;

    ks_mue<<<dim3(160), dim3(256), 0, stream>>>(d1, d2, W, b);
    ks_p  <<<dim3(200), dim3(256), 0, stream>>>();
    ks_out<<<dim3(1),   dim3(256), 0, stream>>>(out);
}

// Round 16
// 72.310 us; speedup vs baseline: 5.2915x; 1.5644x over previous
//
#include <hip/hip_runtime.h>
#include <math.h>

#define N 80
#define D 512
#define NV (N*N)        // 6400
#define CQ 6241.000001  // (n1-1)*(n2-1) + ridge
#define NEU_K 4         // Neumann terms beyond the first (~3.8 digits/term)

// ---- static device scratch ----
__device__ double g_Mp0[N*N];
__device__ float  g_WT[D*D];        // W transposed
__device__ double g_e[2][N*D];      // normalized embeddings
__device__ double g_P[NV];          // p[v], v = i2*80 + i1

// k_pre: blocks 0..255 transpose W into WT (32x32 LDS tiles);
//        blocks 256..455 compute Mp0 = d1 @ d2^T (8 threads/output).
__global__ void k_pre(const float* __restrict__ W,
                      const float* __restrict__ d1, const float* __restrict__ d2) {
    int bid = blockIdx.x;
    int tid = threadIdx.x;
    if (bid < 256) {
        __shared__ float t[32][33];
        int c0 = (bid & 15)*32, k0 = (bid >> 4)*32;
        int tx = tid & 31, ty = tid >> 5;       // 32 x 8
        #pragma unroll
        for (int j = 0; j < 4; ++j) t[ty+8*j][tx] = W[(size_t)(k0+ty+8*j)*D + c0+tx];
        __syncthreads();
        #pragma unroll
        for (int j = 0; j < 4; ++j) g_WT[(size_t)(c0+ty+8*j)*D + k0+tx] = t[tx][ty+8*j];
    } else {
        int gidx = (bid-256)*256 + tid;         // 51200 threads
        int v = gidx >> 3, ch = gidx & 7;
        int i = v / N, j = v % N;
        const float4* A = reinterpret_cast<const float4*>(d1 + (size_t)i*D);
        const float4* B = reinterpret_cast<const float4*>(d2 + (size_t)j*D);
        double a0=0,a1=0,a2=0,a3=0;
        #pragma unroll
        for (int t = 0; t < 16; ++t) {
            float4 x = A[ch + 8*t], y = B[ch + 8*t];
            a0 += (double)x.x*(double)y.x; a1 += (double)x.y*(double)y.y;
            a2 += (double)x.z*(double)y.z; a3 += (double)x.w*(double)y.w;
        }
        double s = (a0+a1)+(a2+a3);
        #pragma unroll
        for (int o = 1; o < 8; o <<= 1) s += __shfl_xor(s, o, 64);
        if (ch == 0) g_Mp0[i*N+j] = s;
    }
}

// k_mue: fused m-row -> lam -> u -> e-row -> row-normalize.
// One block per (g,row), 512 threads, thread k owns output column k.
__global__ void __launch_bounds__(512,1) k_mue(const float* __restrict__ d1,
                                               const float* __restrict__ d2,
                                               const float* __restrict__ b) {
    __shared__ double mp[N];
    __shared__ double su[D];
    __shared__ double red[512];
    __shared__ double red2[512];
    int bid = blockIdx.x;          // 0..159
    int g = bid / N, row = bid % N;
    int tid = threadIdx.x;         // = k
    const float* dsrc = g ? d1 : d2;    // summed rows for m
    const float* dme  = g ? d2 : d1;    // own data row

    if (tid < N) mp[tid] = g ? g_Mp0[tid*N + row] : g_Mp0[row*N + tid];
    __syncthreads();

    // m_k
    double m0=0,m1=0,m2=0,m3=0;
    #pragma unroll 4
    for (int j = 0; j < N; j += 4) {
        m0 += mp[j]   * (double)dsrc[(size_t)j*D     + tid];
        m1 += mp[j+1] * (double)dsrc[(size_t)(j+1)*D + tid];
        m2 += mp[j+2] * (double)dsrc[(size_t)(j+2)*D + tid];
        m3 += mp[j+3] * (double)dsrc[(size_t)(j+3)*D + tid];
    }
    double mk = (m0+m1)+(m2+m3);
    double ak = (double)dme[(size_t)row*D + tid];

    // lam = ||a|| / ||m||
    red[tid] = ak*ak; red2[tid] = mk*mk; __syncthreads();
    for (int o = 256; o > 0; o >>= 1) {
        if (tid < o) { red[tid] += red[tid+o]; red2[tid] += red2[tid+o]; }
        __syncthreads();
    }
    double lam = sqrt(red[0]) / sqrt(red2[0]);
    __syncthreads();

    su[tid] = ak + lam*mk;
    __syncthreads();

    // e_k = relu(b_k + sum_c su[c]*WT[c][k])   (8 chains, coalesced WT)
    const float* wt = g_WT + tid;
    double a0=0,a1=0,a2=0,a3=0,a4=0,a5=0,a6=0,a7=0;
    #pragma unroll 8
    for (int t = 0; t < 64; ++t) {
        int c = t*8;
        a0 += su[c+0]*(double)wt[(size_t)(c+0)*D];
        a1 += su[c+1]*(double)wt[(size_t)(c+1)*D];
        a2 += su[c+2]*(double)wt[(size_t)(c+2)*D];
        a3 += su[c+3]*(double)wt[(size_t)(c+3)*D];
        a4 += su[c+4]*(double)wt[(size_t)(c+4)*D];
        a5 += su[c+5]*(double)wt[(size_t)(c+5)*D];
        a6 += su[c+6]*(double)wt[(size_t)(c+6)*D];
        a7 += su[c+7]*(double)wt[(size_t)(c+7)*D];
    }
    double acc = (double)b[tid] + ((a0+a1)+(a2+a3)) + ((a4+a5)+(a6+a7));
    double ek = acc > 0.0 ? acc : 0.0;

    // row normalize
    red[tid] = ek*ek; __syncthreads();
    for (int o = 256; o > 0; o >>= 1) { if (tid < o) red[tid] += red[tid+o]; __syncthreads(); }
    double nrm = sqrt(red[0]); if (nrm < 1e-12) nrm = 1e-12;
    g_e[g][(size_t)row*D + tid] = ek / nrm;
}

// P[v] = e1n[i1] . e2n[i2] ; 8 threads/output, double2-interleaved
__global__ void k_p() {
    int gidx = blockIdx.x*256 + threadIdx.x;      // 51200 threads
    int v = gidx >> 3, ch = gidx & 7;
    int i1 = v % N, i2 = v / N;
    const double2* a = reinterpret_cast<const double2*>(g_e[0] + (size_t)i1*D);
    const double2* c2 = reinterpret_cast<const double2*>(g_e[1] + (size_t)i2*D);
    double a0=0,a1=0;
    #pragma unroll
    for (int t = 0; t < 32; ++t) {
        double2 x = a[ch + 8*t], y = c2[ch + 8*t];
        a0 += x.x*y.x; a1 += x.y*y.y;
    }
    double s = a0+a1;
    #pragma unroll
    for (int o = 1; o < 8; o <<= 1) s += __shfl_xor(s, o, 64);
    if (ch == 0) g_P[v] = s;
}

// Neumann solve on null(A) + clip + softmax + out; single block
//   r0 = (6402/160) P(p);  x = sum_k M^k r0 / CQ^{k+1},  M(v) = P(p.*v)
__global__ void __launch_bounds__(256,1) k_out(float* __restrict__ out) {
    __shared__ double sv[NV];
    __shared__ double sR[N], sC[N];
    __shared__ double ssc[4];
    const double inv80 = 1.0/80.0, inv6400 = 1.0/6400.0, CHI = 1.0/80.0;
    const double invCQ = 1.0/CQ;
    int tid = threadIdx.x;
    double ploc[25], vv[25], x[25];

    #pragma unroll
    for (int j = 0; j < 25; ++j) { int v = tid + 256*j; ploc[j] = g_P[v]; sv[v] = ploc[j]; }
    __syncthreads();

    if (tid < N) {
        double cs = 0.0; const double* dd = sv + tid*N;
        for (int i1 = 0; i1 < N; ++i1) cs += dd[i1];
        sC[tid] = cs;
    } else if (tid < 2*N) {
        int i1 = tid - N; double rr = 0.0;
        for (int i2 = 0; i2 < N; ++i2) rr += sv[i2*N + i1];
        sR[i1] = rr;
    }
    __syncthreads();
    if (tid == 0) { double s = 0.0; for (int i = 0; i < N; ++i) s += sC[i]; ssc[0] = s; }
    __syncthreads();
    double Tp = ssc[0];
    const double SCALE = 6402.0/160.0;
    #pragma unroll
    for (int j = 0; j < 25; ++j) {
        int v = tid + 256*j; int i1 = v % N, i2 = v / N;
        double rv = SCALE*(ploc[j] - sR[i1]*inv80 - sC[i2]*inv80 + Tp*inv6400);
        vv[j] = rv;
        x[j]  = rv*invCQ;
    }
    __syncthreads();

    for (int k = 0; k < NEU_K; ++k) {
        #pragma unroll
        for (int j = 0; j < 25; ++j) { int v = tid + 256*j; sv[v] = ploc[j]*vv[j]; }
        __syncthreads();
        if (tid < N) {
            double cs = 0.0; const double* dd = sv + tid*N;
            for (int i1 = 0; i1 < N; ++i1) cs += dd[i1];
            sC[tid] = cs;
        } else if (tid < 2*N) {
            int i1 = tid - N; double rr = 0.0;
            for (int i2 = 0; i2 < N; ++i2) rr += sv[i2*N + i1];
            sR[i1] = rr;
        }
        __syncthreads();
        if (tid == 0) { double s = 0.0; for (int i = 0; i < N; ++i) s += sC[i]; ssc[1] = s; }
        __syncthreads();
        double Ty = ssc[1];
        #pragma unroll
        for (int j = 0; j < 25; ++j) {
            int v = tid + 256*j; int i1 = v % N, i2 = v / N;
            double mv = ploc[j]*vv[j] - sR[i1]*inv80 - sC[i2]*inv80 + Ty*inv6400;
            vv[j] = mv*invCQ;
            x[j] += vv[j]*invCQ;
        }
        __syncthreads();
    }

    #pragma unroll
    for (int j = 0; j < 25; ++j) {
        int v = tid + 256*j;
        double z = CHI + x[j];
        sv[v] = z < 0.0 ? 0.0 : (z > 1.0 ? 1.0 : z);
    }
    __syncthreads();
    if (tid < N) {
        double mx = -1e300;
        for (int i2 = 0; i2 < N; ++i2) mx = fmax(mx, sv[i2*N + tid]);
        sR[tid] = mx;
    }
    __syncthreads();
    #pragma unroll
    for (int j = 0; j < 25; ++j) {
        int v = tid + 256*j; int i1 = v % N;
        sv[v] = exp(1000.0*(sv[v] - sR[i1]));
    }
    __syncthreads();
    if (tid < N) {
        double s = 0.0;
        for (int i2 = 0; i2 < N; ++i2) s += sv[i2*N + tid];
        sC[tid] = 1.0 / s;
    }
    __syncthreads();
    #pragma unroll
    for (int j = 0; j < 25; ++j) {
        int v = tid + 256*j; int i1 = v % N, i2 = v / N;
        out[i1*N + i2] = (float)(sv[v] * sC[i1]);
    }
}

extern "C" void kernel_launch(void* const* d_in, const int* in_sizes, int n_in,
                              void* d_out, int out_size, void* d_ws, size_t ws_size,
                              hipStream_t stream) {
    const float* d1 = (const float*)d_in[0];
    const float* d2 = (const float*)d_in[1];
    const float* W  = (const float*)d_in[2];
    const float* b  = (const float*)d_in[3];
    float* out = (float*)d_out;

    k_pre<<<dim3(456), dim3(256), 0, stream>>>(W, d1, d2);
    k_mue<<<dim3(160), dim3(512), 0, stream>>>(d1, d2, b);
    k_p  <<<dim3(200), dim3(256), 0, stream>>>();
    k_out<<<dim3(1),   dim3(256), 0, stream>>>(out);
}

// Round 17
// 58.758 us; speedup vs baseline: 6.5119x; 1.2306x over previous
//
#include <hip/hip_runtime.h>
#include <math.h>

#define N 80
#define D 512
#define NV (N*N)        // 6400
#define CQ 6241.000001  // (n1-1)*(n2-1) + ridge
#define NEU_K 2         // truncation ~ ||r||/CQ^3 ~ 1.6e-10

// ---- static device scratch ----
__device__ double g_Mp0[N*N];
__device__ float  g_WT[D*D];        // W transposed
__device__ double g_e[2][N*D];      // normalized embeddings
__device__ double g_P[NV];          // p[v], v = i2*80 + i1

// k_pre: blocks 0..255 transpose W into WT (32x32 LDS tiles);
//        blocks 256..455 compute Mp0 = d1 @ d2^T (8 threads/output).
__global__ void k_pre(const float* __restrict__ W,
                      const float* __restrict__ d1, const float* __restrict__ d2) {
    int bid = blockIdx.x;
    int tid = threadIdx.x;
    if (bid < 256) {
        __shared__ float t[32][33];
        int c0 = (bid & 15)*32, k0 = (bid >> 4)*32;
        int tx = tid & 31, ty = tid >> 5;       // 32 x 8
        #pragma unroll
        for (int j = 0; j < 4; ++j) t[ty+8*j][tx] = W[(size_t)(k0+ty+8*j)*D + c0+tx];
        __syncthreads();
        #pragma unroll
        for (int j = 0; j < 4; ++j) g_WT[(size_t)(c0+ty+8*j)*D + k0+tx] = t[tx][ty+8*j];
    } else {
        int gidx = (bid-256)*256 + tid;         // 51200 threads
        int v = gidx >> 3, ch = gidx & 7;
        int i = v / N, j = v % N;
        const float4* A = reinterpret_cast<const float4*>(d1 + (size_t)i*D);
        const float4* B = reinterpret_cast<const float4*>(d2 + (size_t)j*D);
        double a0=0,a1=0,a2=0,a3=0;
        #pragma unroll
        for (int t = 0; t < 16; ++t) {
            float4 x = A[ch + 8*t], y = B[ch + 8*t];
            a0 += (double)x.x*(double)y.x; a1 += (double)x.y*(double)y.y;
            a2 += (double)x.z*(double)y.z; a3 += (double)x.w*(double)y.w;
        }
        double s = (a0+a1)+(a2+a3);
        #pragma unroll
        for (int o = 1; o < 8; o <<= 1) s += __shfl_xor(s, o, 64);
        if (ch == 0) g_Mp0[i*N+j] = s;
    }
}

// block-wide (512 thr) sum via wave shuffle + 8-slot LDS; 1 barrier + broadcast
__device__ __forceinline__ double bsum512(double v, double* w8, int tid) {
    #pragma unroll
    for (int o = 1; o < 64; o <<= 1) v += __shfl_xor(v, o, 64);
    if ((tid & 63) == 0) w8[tid >> 6] = v;
    __syncthreads();
    return ((w8[0]+w8[1])+(w8[2]+w8[3])) + ((w8[4]+w8[5])+(w8[6]+w8[7]));
}

// k_mue: fused m-row -> lam -> u -> e-row -> row-normalize.
// One block per (g,row), 512 threads, thread k owns output column k.
__global__ void __launch_bounds__(512,1) k_mue(const float* __restrict__ d1,
                                               const float* __restrict__ d2,
                                               const float* __restrict__ b) {
    __shared__ double mp[N];
    __shared__ double su[D];
    __shared__ double w8a[8], w8b[8];
    int bid = blockIdx.x;          // 0..159
    int g = bid / N, row = bid % N;
    int tid = threadIdx.x;         // = k
    const float* dsrc = g ? d1 : d2;    // summed rows for m
    const float* dme  = g ? d2 : d1;    // own data row

    if (tid < N) mp[tid] = g ? g_Mp0[tid*N + row] : g_Mp0[row*N + tid];
    __syncthreads();

    // m_k  (8 chains over 80 rows)
    double m0=0,m1=0,m2=0,m3=0,m4=0,m5=0,m6=0,m7=0;
    #pragma unroll 2
    for (int j = 0; j < N; j += 8) {
        m0 += mp[j]   * (double)dsrc[(size_t)j*D     + tid];
        m1 += mp[j+1] * (double)dsrc[(size_t)(j+1)*D + tid];
        m2 += mp[j+2] * (double)dsrc[(size_t)(j+2)*D + tid];
        m3 += mp[j+3] * (double)dsrc[(size_t)(j+3)*D + tid];
        m4 += mp[j+4] * (double)dsrc[(size_t)(j+4)*D + tid];
        m5 += mp[j+5] * (double)dsrc[(size_t)(j+5)*D + tid];
        m6 += mp[j+6] * (double)dsrc[(size_t)(j+6)*D + tid];
        m7 += mp[j+7] * (double)dsrc[(size_t)(j+7)*D + tid];
    }
    double mk = ((m0+m1)+(m2+m3)) + ((m4+m5)+(m6+m7));
    double ak = (double)dme[(size_t)row*D + tid];

    // lam = ||a|| / ||m||   (two shuffle-reductions, 1 barrier each)
    double sa = bsum512(ak*ak, w8a, tid);
    double sm = bsum512(mk*mk, w8b, tid);
    double lam = sqrt(sa) / sqrt(sm);
    __syncthreads();            // w8a/w8b reuse guard
    su[tid] = ak + lam*mk;
    __syncthreads();

    // e_k = relu(b_k + sum_c su[c]*WT[c][k])   (16 chains, coalesced WT)
    const float* wt = g_WT + tid;
    double a0=0,a1=0,a2=0,a3=0,a4=0,a5=0,a6=0,a7=0;
    double b0=0,b1=0,b2=0,b3=0,b4=0,b5=0,b6=0,b7=0;
    #pragma unroll 4
    for (int t = 0; t < 32; ++t) {
        int c = t*16;
        a0 += su[c+0]*(double)wt[(size_t)(c+0)*D];
        a1 += su[c+1]*(double)wt[(size_t)(c+1)*D];
        a2 += su[c+2]*(double)wt[(size_t)(c+2)*D];
        a3 += su[c+3]*(double)wt[(size_t)(c+3)*D];
        a4 += su[c+4]*(double)wt[(size_t)(c+4)*D];
        a5 += su[c+5]*(double)wt[(size_t)(c+5)*D];
        a6 += su[c+6]*(double)wt[(size_t)(c+6)*D];
        a7 += su[c+7]*(double)wt[(size_t)(c+7)*D];
        b0 += su[c+8]*(double)wt[(size_t)(c+8)*D];
        b1 += su[c+9]*(double)wt[(size_t)(c+9)*D];
        b2 += su[c+10]*(double)wt[(size_t)(c+10)*D];
        b3 += su[c+11]*(double)wt[(size_t)(c+11)*D];
        b4 += su[c+12]*(double)wt[(size_t)(c+12)*D];
        b5 += su[c+13]*(double)wt[(size_t)(c+13)*D];
        b6 += su[c+14]*(double)wt[(size_t)(c+14)*D];
        b7 += su[c+15]*(double)wt[(size_t)(c+15)*D];
    }
    double acc = (double)b[tid]
               + (((a0+a1)+(a2+a3)) + ((a4+a5)+(a6+a7)))
               + (((b0+b1)+(b2+b3)) + ((b4+b5)+(b6+b7)));
    double ek = acc > 0.0 ? acc : 0.0;

    // row normalize (shuffle reduction)
    double sn = bsum512(ek*ek, w8a, tid);
    double nrm = sqrt(sn); if (nrm < 1e-12) nrm = 1e-12;
    g_e[g][(size_t)row*D + tid] = ek / nrm;
}

// P[v] = e1n[i1] . e2n[i2] ; 8 threads/output, double2-interleaved, 4 chains
__global__ void k_p() {
    int gidx = blockIdx.x*256 + threadIdx.x;      // 51200 threads
    int v = gidx >> 3, ch = gidx & 7;
    int i1 = v % N, i2 = v / N;
    const double2* a = reinterpret_cast<const double2*>(g_e[0] + (size_t)i1*D);
    const double2* c2 = reinterpret_cast<const double2*>(g_e[1] + (size_t)i2*D);
    double a0=0,a1=0,a2=0,a3=0;
    #pragma unroll
    for (int t = 0; t < 32; t += 2) {
        double2 x = a[ch + 8*t],     y = c2[ch + 8*t];
        double2 x1 = a[ch + 8*t+8],  y1 = c2[ch + 8*t+8];
        a0 += x.x*y.x;  a1 += x.y*y.y;
        a2 += x1.x*y1.x; a3 += x1.y*y1.y;
    }
    double s = (a0+a1)+(a2+a3);
    #pragma unroll
    for (int o = 1; o < 8; o <<= 1) s += __shfl_xor(s, o, 64);
    if (ch == 0) g_P[v] = s;
}

// Neumann solve on null(A) + clip + softmax + out; single block.
// Final store coalesced via padded LDS transpose.
__global__ void __launch_bounds__(256,1) k_out(float* __restrict__ out) {
    __shared__ double sv[NV];
    __shared__ double sR[N], sC[N];
    __shared__ double ssc[4];
    __shared__ float  sox[N*(N+1)];   // padded transpose buffer (80x81 floats)
    const double inv80 = 1.0/80.0, inv6400 = 1.0/6400.0, CHI = 1.0/80.0;
    const double invCQ = 1.0/CQ;
    int tid = threadIdx.x;
    double ploc[25], vv[25], x[25];

    #pragma unroll
    for (int j = 0; j < 25; ++j) { int v = tid + 256*j; ploc[j] = g_P[v]; sv[v] = ploc[j]; }
    __syncthreads();

    if (tid < N) {
        double cs = 0.0; const double* dd = sv + tid*N;
        for (int i1 = 0; i1 < N; ++i1) cs += dd[i1];
        sC[tid] = cs;
    } else if (tid < 2*N) {
        int i1 = tid - N; double rr = 0.0;
        for (int i2 = 0; i2 < N; ++i2) rr += sv[i2*N + i1];
        sR[i1] = rr;
    }
    __syncthreads();
    if (tid == 0) { double s = 0.0; for (int i = 0; i < N; ++i) s += sC[i]; ssc[0] = s; }
    __syncthreads();
    double Tp = ssc[0];
    const double SCALE = 6402.0/160.0;
    #pragma unroll
    for (int j = 0; j < 25; ++j) {
        int v = tid + 256*j; int i1 = v % N, i2 = v / N;
        double rv = SCALE*(ploc[j] - sR[i1]*inv80 - sC[i2]*inv80 + Tp*inv6400);
        vv[j] = rv;
        x[j]  = rv*invCQ;
    }
    __syncthreads();

    for (int k = 0; k < NEU_K; ++k) {
        #pragma unroll
        for (int j = 0; j < 25; ++j) { int v = tid + 256*j; sv[v] = ploc[j]*vv[j]; }
        __syncthreads();
        if (tid < N) {
            double cs = 0.0; const double* dd = sv + tid*N;
            for (int i1 = 0; i1 < N; ++i1) cs += dd[i1];
            sC[tid] = cs;
        } else if (tid < 2*N) {
            int i1 = tid - N; double rr = 0.0;
            for (int i2 = 0; i2 < N; ++i2) rr += sv[i2*N + i1];
            sR[i1] = rr;
        }
        __syncthreads();
        if (tid == 0) { double s = 0.0; for (int i = 0; i < N; ++i) s += sC[i]; ssc[1] = s; }
        __syncthreads();
        double Ty = ssc[1];
        #pragma unroll
        for (int j = 0; j < 25; ++j) {
            int v = tid + 256*j; int i1 = v % N, i2 = v / N;
            double mv = ploc[j]*vv[j] - sR[i1]*inv80 - sC[i2]*inv80 + Ty*inv6400;
            vv[j] = mv*invCQ;
            x[j] += vv[j]*invCQ;
        }
        __syncthreads();
    }

    // z = clip(1/80 + x)
    #pragma unroll
    for (int j = 0; j < 25; ++j) {
        int v = tid + 256*j;
        double z = CHI + x[j];
        sv[v] = z < 0.0 ? 0.0 : (z > 1.0 ? 1.0 : z);
    }
    __syncthreads();
    // per-column (i1) max over i2
    if (tid < N) {
        double mx = -1e300;
        for (int i2 = 0; i2 < N; ++i2) mx = fmax(mx, sv[i2*N + tid]);
        sR[tid] = mx;
    }
    __syncthreads();
    #pragma unroll
    for (int j = 0; j < 25; ++j) {
        int v = tid + 256*j; int i1 = v % N;
        sv[v] = exp(1000.0*(sv[v] - sR[i1]));
    }
    __syncthreads();
    if (tid < N) {
        double s = 0.0;
        for (int i2 = 0; i2 < N; ++i2) s += sv[i2*N + tid];
        sC[tid] = 1.0 / s;
    }
    __syncthreads();
    // transpose into padded float buffer: sox[i1][i2] = sv[i2*N+i1]*sC[i1]
    #pragma unroll
    for (int j = 0; j < 25; ++j) {
        int v = tid + 256*j; int i1 = v % N, i2 = v / N;
        sox[i1*(N+1) + i2] = (float)(sv[v] * sC[i1]);
    }
    __syncthreads();
    // coalesced stores: consecutive tid -> consecutive out index
    for (int w = tid; w < NV; w += 256) {
        int i1 = w / N, i2 = w % N;
        out[w] = sox[i1*(N+1) + i2];
    }
}

extern "C" void kernel_launch(void* const* d_in, const int* in_sizes, int n_in,
                              void* d_out, int out_size, void* d_ws, size_t ws_size,
                              hipStream_t stream) {
    const float* d1 = (const float*)d_in[0];
    const float* d2 = (const float*)d_in[1];
    const float* W  = (const float*)d_in[2];
    const float* b  = (const float*)d_in[3];
    float* out = (float*)d_out;

    k_pre<<<dim3(456), dim3(256), 0, stream>>>(W, d1, d2);
    k_mue<<<dim3(160), dim3(512), 0, stream>>>(d1, d2, b);
    k_p  <<<dim3(200), dim3(256), 0, stream>>>();
    k_out<<<dim3(1),   dim3(256), 0, stream>>>(out);
}